// Round 1
// baseline (183.724 us; speedup 1.0000x reference)
//
#include <hip/hip_runtime.h>
#include <math.h>

#define LSEQ 1024
#define EDIM 512
#define NHEAD 16      // bsz * 8
#define HD 64
#define ROWS 2048     // LSEQ * bsz
#define CCH 32        // chunk length
#define NCH 32        // chunks per head
#define DFEAT 128     // doubled feature dim (sin|cos)

// ---------------- QKV projection: Y = relu?(X @ W^T + b), scatter to head layout
__global__ __launch_bounds__(256) void qkv_proj_kernel(
    const float* __restrict__ X,
    const float* __restrict__ Wq, const float* __restrict__ bq,
    const float* __restrict__ Wk, const float* __restrict__ bk,
    const float* __restrict__ Wv, const float* __restrict__ bv,
    float* __restrict__ qf, float* __restrict__ kf, float* __restrict__ vf)
{
    const int z = blockIdx.z;
    const float* __restrict__ W    = (z == 0) ? Wq : (z == 1) ? Wk : Wv;
    const float* __restrict__ bias = (z == 0) ? bq : (z == 1) ? bk : bv;
    const int r0 = blockIdx.x * 64;
    const int j0 = blockIdx.y * 64;
    __shared__ float As[16][68];
    __shared__ float Bs[16][68];
    const int t = threadIdx.x;
    const int mm_ld = t >> 2;          // 0..63
    const int kk_ld = (t & 3) << 2;    // 0,4,8,12
    const int mm0 = (t & 15) << 2;     // row tile
    const int nn0 = (t >> 4) << 2;     // col tile
    float acc[4][4] = {};

    for (int kb = 0; kb < EDIM; kb += 16) {
        float4 av  = *(const float4*)&X[(size_t)(r0 + mm_ld) * EDIM + kb + kk_ld];
        float4 bv4 = *(const float4*)&W[(size_t)(j0 + mm_ld) * EDIM + kb + kk_ld];
        __syncthreads();
        As[kk_ld + 0][mm_ld] = av.x;  As[kk_ld + 1][mm_ld] = av.y;
        As[kk_ld + 2][mm_ld] = av.z;  As[kk_ld + 3][mm_ld] = av.w;
        Bs[kk_ld + 0][mm_ld] = bv4.x; Bs[kk_ld + 1][mm_ld] = bv4.y;
        Bs[kk_ld + 2][mm_ld] = bv4.z; Bs[kk_ld + 3][mm_ld] = bv4.w;
        __syncthreads();
        #pragma unroll
        for (int kk = 0; kk < 16; ++kk) {
            float4 a = *(const float4*)&As[kk][mm0];
            float4 b = *(const float4*)&Bs[kk][nn0];
            acc[0][0] += a.x * b.x; acc[0][1] += a.x * b.y; acc[0][2] += a.x * b.z; acc[0][3] += a.x * b.w;
            acc[1][0] += a.y * b.x; acc[1][1] += a.y * b.y; acc[1][2] += a.y * b.z; acc[1][3] += a.y * b.w;
            acc[2][0] += a.z * b.x; acc[2][1] += a.z * b.y; acc[2][2] += a.z * b.z; acc[2][3] += a.z * b.w;
            acc[3][0] += a.w * b.x; acc[3][1] += a.w * b.y; acc[3][2] += a.w * b.z; acc[3][3] += a.w * b.w;
        }
    }

    #pragma unroll
    for (int i = 0; i < 4; ++i) {
        const int r = r0 + mm0 + i;
        const int l = r >> 1, bb = r & 1;
        float sv = 0.f, cv = 0.f;
        if (z < 2) {
            float ang = 1.5707963267948966f * (float)(l + 1) * (1.0f / 1024.0f);
            sincosf(ang, &sv, &cv);
        }
        #pragma unroll
        for (int j = 0; j < 4; ++j) {
            const int jg = j0 + nn0 + j;
            float y = acc[i][j] + bias[jg];
            const int h = jg >> 6, d = jg & 63;
            const int n = bb * 8 + h;
            if (z == 2) {
                vf[(size_t)(n * LSEQ + l) * HD + d] = y;
            } else {
                y = fmaxf(y, 0.f);
                float* dst = (z == 0) ? qf : kf;
                size_t base = (size_t)(n * LSEQ + l) * DFEAT;
                dst[base + d]      = y * sv;
                dst[base + d + 64] = y * cv;
            }
        }
    }
}

// ---------------- per-chunk KV outer-product sums (128x64) + K1 sums (128)
__global__ __launch_bounds__(256) void chunk_sum_kernel(
    const float* __restrict__ kf, const float* __restrict__ vf,
    float* __restrict__ KV, float* __restrict__ K1)
{
    const int n = blockIdx.x >> 5;
    const int c = blockIdx.x & 31;
    __shared__ float ks[32][132];
    __shared__ float vs[32][68];
    const int t = threadIdx.x;
    const float* kbase = kf + (size_t)(n * LSEQ + c * CCH) * DFEAT;
    const float* vbase = vf + (size_t)(n * LSEQ + c * CCH) * HD;
    #pragma unroll
    for (int it = 0; it < 4; ++it) {
        int idx = it * 256 + t;
        int row = idx >> 5, c4 = (idx & 31) << 2;
        *(float4*)&ks[row][c4] = *(const float4*)&kbase[row * DFEAT + c4];
    }
    #pragma unroll
    for (int it = 0; it < 2; ++it) {
        int idx = it * 256 + t;
        int row = idx >> 4, c4 = (idx & 15) << 2;
        *(float4*)&vs[row][c4] = *(const float4*)&vbase[row * HD + c4];
    }
    __syncthreads();
    const int m0 = (t & 15) << 2;
    const int d0 = (t >> 4) << 3;
    float acc[8][4] = {};
    #pragma unroll 4
    for (int l = 0; l < CCH; ++l) {
        float4 vv = *(const float4*)&vs[l][m0];
        #pragma unroll
        for (int i = 0; i < 8; ++i) {
            float kvv = ks[l][d0 + i];
            acc[i][0] += kvv * vv.x; acc[i][1] += kvv * vv.y;
            acc[i][2] += kvv * vv.z; acc[i][3] += kvv * vv.w;
        }
    }
    float* out = KV + (size_t)(n * NCH + c) * (DFEAT * HD);
    #pragma unroll
    for (int i = 0; i < 8; ++i) {
        float4 o = {acc[i][0], acc[i][1], acc[i][2], acc[i][3]};
        *(float4*)&out[(d0 + i) * HD + m0] = o;
    }
    if (t < 128) {
        float s = 0.f;
        #pragma unroll
        for (int l = 0; l < CCH; ++l) s += ks[l][t];
        K1[(size_t)(n * NCH + c) * DFEAT + t] = s;
    }
}

// ---------------- in-place exclusive prefix over chunks (KV and K1)
__global__ __launch_bounds__(256) void prefix_kernel(float* __restrict__ KV, float* __restrict__ K1)
{
    const int bx = blockIdx.x, t = threadIdx.x;
    if (bx < 512) {
        const int n = bx >> 5;
        const int idx = (bx & 31) * 256 + t;        // 0..8191
        float* base = KV + (size_t)n * NCH * (DFEAT * HD) + idx;
        float run = 0.f;
        for (int c = 0; c < NCH; ++c) {
            float vv = base[(size_t)c * (DFEAT * HD)];
            base[(size_t)c * (DFEAT * HD)] = run;
            run += vv;
        }
    } else {
        const int idx = (bx - 512) * 256 + t;       // 0..2047
        const int n = idx >> 7, d = idx & 127;
        float* base = K1 + (size_t)n * NCH * DFEAT + d;
        float run = 0.f;
        for (int c = 0; c < NCH; ++c) {
            float vv = base[c * DFEAT];
            base[c * DFEAT] = run;
            run += vv;
        }
    }
}

// ---------------- intra-chunk causal attention + external prefix + normalize
__global__ __launch_bounds__(256) void attn_chunk_kernel(
    const float* __restrict__ qf, const float* __restrict__ kf,
    const float* __restrict__ vf, const float* __restrict__ KVpre,
    const float* __restrict__ K1pre, float* __restrict__ attnM)
{
    const int n = blockIdx.x >> 5;
    const int c = blockIdx.x & 31;
    __shared__ float Qs[32][132];
    __shared__ float Ks[32][132];
    __shared__ float Vs[32][68];
    __shared__ float Asm[32][36];
    __shared__ float K1s[128];
    __shared__ float rowsum[32];
    const int t = threadIdx.x;
    const float* qbase = qf + (size_t)(n * LSEQ + c * CCH) * DFEAT;
    const float* kbase = kf + (size_t)(n * LSEQ + c * CCH) * DFEAT;
    const float* vbase = vf + (size_t)(n * LSEQ + c * CCH) * HD;
    #pragma unroll
    for (int it = 0; it < 4; ++it) {
        int idx = it * 256 + t;
        int row = idx >> 5, c4 = (idx & 31) << 2;
        *(float4*)&Qs[row][c4] = *(const float4*)&qbase[row * DFEAT + c4];
        *(float4*)&Ks[row][c4] = *(const float4*)&kbase[row * DFEAT + c4];
    }
    #pragma unroll
    for (int it = 0; it < 2; ++it) {
        int idx = it * 256 + t;
        int row = idx >> 4, c4 = (idx & 15) << 2;
        *(float4*)&Vs[row][c4] = *(const float4*)&vbase[row * HD + c4];
    }
    if (t < 128) K1s[t] = K1pre[(size_t)(n * NCH + c) * DFEAT + t];
    __syncthreads();

    // phase A: A[l][lp] = q_l . k_lp (causal-masked), plus row sums
    {
        const int l = t >> 3;
        const int lp0 = (t & 7) << 2;
        float a4[4] = {0.f, 0.f, 0.f, 0.f};
        #pragma unroll 4
        for (int d = 0; d < DFEAT; ++d) {
            float qv = Qs[l][d];
            a4[0] += qv * Ks[lp0 + 0][d];
            a4[1] += qv * Ks[lp0 + 1][d];
            a4[2] += qv * Ks[lp0 + 2][d];
            a4[3] += qv * Ks[lp0 + 3][d];
        }
        float part = 0.f;
        #pragma unroll
        for (int j = 0; j < 4; ++j) {
            float m = (lp0 + j <= l) ? a4[j] : 0.f;
            Asm[l][lp0 + j] = m;
            part += m;
        }
        part += __shfl_xor(part, 1);
        part += __shfl_xor(part, 2);
        part += __shfl_xor(part, 4);
        if ((t & 7) == 0) rowsum[l] = part;
    }
    __syncthreads();

    // phase C: qkv = Q @ S_prev + A_masked @ V ; denom = q.K1_prev + rowsum
    const int m0 = (t & 15) << 2;
    const int lA = (t >> 4) << 1;
    const float* Sp = KVpre + (size_t)(n * NCH + c) * (DFEAT * HD);
    float acc0[4] = {}, acc1[4] = {};
    float dex0 = 0.f, dex1 = 0.f;
    #pragma unroll 4
    for (int d = 0; d < DFEAT; ++d) {
        float q0 = Qs[lA][d], q1 = Qs[lA + 1][d];
        float4 sv = *(const float4*)&Sp[d * HD + m0];
        acc0[0] += q0 * sv.x; acc0[1] += q0 * sv.y; acc0[2] += q0 * sv.z; acc0[3] += q0 * sv.w;
        acc1[0] += q1 * sv.x; acc1[1] += q1 * sv.y; acc1[2] += q1 * sv.z; acc1[3] += q1 * sv.w;
        float k1 = K1s[d];
        dex0 += q0 * k1; dex1 += q1 * k1;
    }
    #pragma unroll
    for (int lp = 0; lp < CCH; ++lp) {
        float a0 = Asm[lA][lp], a1 = Asm[lA + 1][lp];
        float4 vv = *(const float4*)&Vs[lp][m0];
        acc0[0] += a0 * vv.x; acc0[1] += a0 * vv.y; acc0[2] += a0 * vv.z; acc0[3] += a0 * vv.w;
        acc1[0] += a1 * vv.x; acc1[1] += a1 * vv.y; acc1[2] += a1 * vv.z; acc1[3] += a1 * vv.w;
    }
    const float den0 = fmaxf(rowsum[lA] + dex0, 1e-6f);
    const float den1 = fmaxf(rowsum[lA + 1] + dex1, 1e-6f);
    const int bb = n >> 3, h = n & 7;
    {
        const int lg = c * CCH + lA;
        int r = lg * 2 + bb;
        float4 o0 = {acc0[0] / den0, acc0[1] / den0, acc0[2] / den0, acc0[3] / den0};
        *(float4*)&attnM[(size_t)r * EDIM + h * 64 + m0] = o0;
        r = (lg + 1) * 2 + bb;
        float4 o1 = {acc1[0] / den1, acc1[1] / den1, acc1[2] / den1, acc1[3] / den1};
        *(float4*)&attnM[(size_t)r * EDIM + h * 64 + m0] = o1;
    }
}

// ---------------- output projection: out = Am @ Wo^T + bo
__global__ __launch_bounds__(256) void out_proj_kernel(
    const float* __restrict__ Am, const float* __restrict__ Wo,
    const float* __restrict__ bo, float* __restrict__ out)
{
    const int r0 = blockIdx.x * 64;
    const int j0 = blockIdx.y * 64;
    __shared__ float As[16][68];
    __shared__ float Bs[16][68];
    const int t = threadIdx.x;
    const int mm_ld = t >> 2;
    const int kk_ld = (t & 3) << 2;
    const int mm0 = (t & 15) << 2;
    const int nn0 = (t >> 4) << 2;
    float acc[4][4] = {};

    for (int kb = 0; kb < EDIM; kb += 16) {
        float4 av  = *(const float4*)&Am[(size_t)(r0 + mm_ld) * EDIM + kb + kk_ld];
        float4 bv4 = *(const float4*)&Wo[(size_t)(j0 + mm_ld) * EDIM + kb + kk_ld];
        __syncthreads();
        As[kk_ld + 0][mm_ld] = av.x;  As[kk_ld + 1][mm_ld] = av.y;
        As[kk_ld + 2][mm_ld] = av.z;  As[kk_ld + 3][mm_ld] = av.w;
        Bs[kk_ld + 0][mm_ld] = bv4.x; Bs[kk_ld + 1][mm_ld] = bv4.y;
        Bs[kk_ld + 2][mm_ld] = bv4.z; Bs[kk_ld + 3][mm_ld] = bv4.w;
        __syncthreads();
        #pragma unroll
        for (int kk = 0; kk < 16; ++kk) {
            float4 a = *(const float4*)&As[kk][mm0];
            float4 b = *(const float4*)&Bs[kk][nn0];
            acc[0][0] += a.x * b.x; acc[0][1] += a.x * b.y; acc[0][2] += a.x * b.z; acc[0][3] += a.x * b.w;
            acc[1][0] += a.y * b.x; acc[1][1] += a.y * b.y; acc[1][2] += a.y * b.z; acc[1][3] += a.y * b.w;
            acc[2][0] += a.z * b.x; acc[2][1] += a.z * b.y; acc[2][2] += a.z * b.z; acc[2][3] += a.z * b.w;
            acc[3][0] += a.w * b.x; acc[3][1] += a.w * b.y; acc[3][2] += a.w * b.z; acc[3][3] += a.w * b.w;
        }
    }

    float4 b4 = *(const float4*)&bo[j0 + nn0];
    #pragma unroll
    for (int i = 0; i < 4; ++i) {
        const int r = r0 + mm0 + i;
        float4 o = {acc[i][0] + b4.x, acc[i][1] + b4.y, acc[i][2] + b4.z, acc[i][3] + b4.w};
        *(float4*)&out[(size_t)r * EDIM + j0 + nn0] = o;
    }
}

extern "C" void kernel_launch(void* const* d_in, const int* in_sizes, int n_in,
                              void* d_out, int out_size, void* d_ws, size_t ws_size,
                              hipStream_t stream) {
    const float* X  = (const float*)d_in[0];
    const float* Wq = (const float*)d_in[1]; const float* bq = (const float*)d_in[2];
    const float* Wk = (const float*)d_in[3]; const float* bk = (const float*)d_in[4];
    const float* Wv = (const float*)d_in[5]; const float* bv = (const float*)d_in[6];
    const float* Wo = (const float*)d_in[7]; const float* bo = (const float*)d_in[8];
    float* out = (float*)d_out;
    float* ws = (float*)d_ws;
    float* qf = ws;                  // 16*1024*128 = 2097152
    float* kf = ws + 2097152;        // 2097152
    float* vf = ws + 4194304;        // 16*1024*64 = 1048576
    float* KV = ws + 5242880;        // 16*32*8192 = 4194304
    float* K1 = ws + 9437184;        // 16*32*128 = 65536
    float* Am = ws + 9502720;        // 2048*512 = 1048576  (total 42.2 MB)

    hipLaunchKernelGGL(qkv_proj_kernel, dim3(32, 8, 3), dim3(256), 0, stream,
                       X, Wq, bq, Wk, bk, Wv, bv, qf, kf, vf);
    hipLaunchKernelGGL(chunk_sum_kernel, dim3(512), dim3(256), 0, stream, kf, vf, KV, K1);
    hipLaunchKernelGGL(prefix_kernel, dim3(520), dim3(256), 0, stream, KV, K1);
    hipLaunchKernelGGL(attn_chunk_kernel, dim3(512), dim3(256), 0, stream,
                       qf, kf, vf, KV, K1, Am);
    hipLaunchKernelGGL(out_proj_kernel, dim3(32, 8), dim3(256), 0, stream, Am, Wo, bo, out);
}

// Round 2
// 137.869 us; speedup vs baseline: 1.3326x; 1.3326x over previous
//
#include <hip/hip_runtime.h>
#include <math.h>

#define LSEQ 1024
#define EDIM 512
#define HD 64
#define CCH 32        // chunk length
#define NCH 32        // chunks per head
#define DFEAT 128     // doubled feature dim (sin|cos)

typedef unsigned short u16;
typedef short bf16x8 __attribute__((ext_vector_type(8)));
typedef float f32x4 __attribute__((ext_vector_type(4)));

__device__ __forceinline__ u16 f2bf(float f) {
    unsigned u = __float_as_uint(f);
    unsigned r = (u + 0x7fffu + ((u >> 16) & 1u)) >> 16;
    return (u16)r;
}

__device__ __forceinline__ void async16(short* lds, const void* g) {
    __builtin_amdgcn_global_load_lds(
        (const __attribute__((address_space(1))) unsigned int*)g,
        (__attribute__((address_space(3))) unsigned int*)(void*)lds, 16, 0, 0);
}

// ---------------- cast fp32 -> bf16 for X and the 4 weight matrices
__global__ __launch_bounds__(256) void cast_kernel(
    const float* __restrict__ X,  const float* __restrict__ Wq,
    const float* __restrict__ Wk, const float* __restrict__ Wv,
    const float* __restrict__ Wo, u16* __restrict__ Xb, u16* __restrict__ Wb)
{
    int i = blockIdx.x * 256 + threadIdx.x;   // one float4 group per thread
    const float* src; u16* dst; int off;
    if (i < 262144)      { src = X;  dst = Xb;          off = i; }
    else if (i < 327680) { src = Wq; dst = Wb;          off = i - 262144; }
    else if (i < 393216) { src = Wk; dst = Wb + 262144; off = i - 327680; }
    else if (i < 458752) { src = Wv; dst = Wb + 524288; off = i - 393216; }
    else                 { src = Wo; dst = Wb + 786432; off = i - 458752; }
    float4 v = *(const float4*)&src[(size_t)off * 4];
    ushort4 o; o.x = f2bf(v.x); o.y = f2bf(v.y); o.z = f2bf(v.z); o.w = f2bf(v.w);
    *(ushort4*)&dst[(size_t)off * 4] = o;
}

// ---------------- QKV projection via bf16 MFMA: Y = relu?(X @ W^T + b) + feature map
__global__ __launch_bounds__(256) void qkv_mfma_kernel(
    const u16* __restrict__ Xb, const u16* __restrict__ Wb,
    const float* __restrict__ bq, const float* __restrict__ bk, const float* __restrict__ bv,
    float* __restrict__ qf, float* __restrict__ kf, float* __restrict__ vf)
{
    const int z = blockIdx.z;
    const u16* __restrict__ W = Wb + (size_t)z * 262144;
    const float* __restrict__ bias = (z == 0) ? bq : (z == 1) ? bk : bv;
    const int r0 = blockIdx.x * 128;
    const int j0 = blockIdx.y * 128;
    __shared__ short As[128 * 32];
    __shared__ short Bs[128 * 32];
    const int t = threadIdx.x;
    const int wave = t >> 6, lane = t & 63;
    const int wm = (wave & 1) * 64, wn = (wave >> 1) * 64;
    const int cl = lane & 15, rg4 = lane >> 4;
    f32x4 acc[4][4];
    #pragma unroll
    for (int fi = 0; fi < 4; ++fi)
        #pragma unroll
        for (int fj = 0; fj < 4; ++fj) acc[fi][fj] = (f32x4){0.f, 0.f, 0.f, 0.f};

    for (int kb = 0; kb < 512; kb += 32) {
        #pragma unroll
        for (int i = 0; i < 2; ++i) {
            int chunk = i * 256 + t;
            int row = chunk >> 2, kg = chunk & 3;
            async16(&As[(size_t)(i * 256 + wave * 64) * 8], Xb + (size_t)(r0 + row) * 512 + kb + kg * 8);
            async16(&Bs[(size_t)(i * 256 + wave * 64) * 8], W  + (size_t)(j0 + row) * 512 + kb + kg * 8);
        }
        __syncthreads();
        bf16x8 af[4], bg[4];
        #pragma unroll
        for (int f = 0; f < 4; ++f) {
            af[f] = *(const bf16x8*)&As[(wm + f * 16 + cl) * 32 + rg4 * 8];
            bg[f] = *(const bf16x8*)&Bs[(wn + f * 16 + cl) * 32 + rg4 * 8];
        }
        #pragma unroll
        for (int fi = 0; fi < 4; ++fi)
            #pragma unroll
            for (int fj = 0; fj < 4; ++fj)
                acc[fi][fj] = __builtin_amdgcn_mfma_f32_16x16x32_bf16(af[fi], bg[fj], acc[fi][fj], 0, 0, 0);
        __syncthreads();
    }

    float biasv[4];
    #pragma unroll
    for (int fj = 0; fj < 4; ++fj) biasv[fj] = bias[j0 + wn + fj * 16 + cl];
    #pragma unroll
    for (int fi = 0; fi < 4; ++fi) {
        #pragma unroll
        for (int rr = 0; rr < 4; ++rr) {
            const int row_g = r0 + wm + fi * 16 + rg4 * 4 + rr;
            const int l = row_g >> 1, bb = row_g & 1;
            if (z < 2) {
                float ang = 1.5707963267948966f * (float)(l + 1) * (1.0f / 1024.0f);
                float sv, cv;
                sincosf(ang, &sv, &cv);
                float* __restrict__ dst = (z == 0) ? qf : kf;
                #pragma unroll
                for (int fj = 0; fj < 4; ++fj) {
                    const int jg = j0 + wn + fj * 16 + cl;
                    float y = fmaxf(acc[fi][fj][rr] + biasv[fj], 0.f);
                    const int h = jg >> 6, d = jg & 63;
                    size_t base = (size_t)((bb * 8 + h) * LSEQ + l) * DFEAT;
                    dst[base + d]      = y * sv;
                    dst[base + d + 64] = y * cv;
                }
            } else {
                #pragma unroll
                for (int fj = 0; fj < 4; ++fj) {
                    const int jg = j0 + wn + fj * 16 + cl;
                    float y = acc[fi][fj][rr] + biasv[fj];
                    const int h = jg >> 6, d = jg & 63;
                    vf[(size_t)((bb * 8 + h) * LSEQ + l) * HD + d] = y;
                }
            }
        }
    }
}

// ---------------- per-chunk KV outer-product sums (128x64) + K1 sums (128)
__global__ __launch_bounds__(256) void chunk_sum_kernel(
    const float* __restrict__ kf, const float* __restrict__ vf,
    float* __restrict__ KV, float* __restrict__ K1)
{
    const int n = blockIdx.x >> 5;
    const int c = blockIdx.x & 31;
    __shared__ float ks[32][132];
    __shared__ float vs[32][68];
    const int t = threadIdx.x;
    const float* kbase = kf + (size_t)(n * LSEQ + c * CCH) * DFEAT;
    const float* vbase = vf + (size_t)(n * LSEQ + c * CCH) * HD;
    #pragma unroll
    for (int it = 0; it < 4; ++it) {
        int idx = it * 256 + t;
        int row = idx >> 5, c4 = (idx & 31) << 2;
        *(float4*)&ks[row][c4] = *(const float4*)&kbase[row * DFEAT + c4];
    }
    #pragma unroll
    for (int it = 0; it < 2; ++it) {
        int idx = it * 256 + t;
        int row = idx >> 4, c4 = (idx & 15) << 2;
        *(float4*)&vs[row][c4] = *(const float4*)&vbase[row * HD + c4];
    }
    __syncthreads();
    const int m0 = (t & 15) << 2;
    const int d0 = (t >> 4) << 3;
    float acc[8][4] = {};
    #pragma unroll 4
    for (int l = 0; l < CCH; ++l) {
        float4 vv = *(const float4*)&vs[l][m0];
        #pragma unroll
        for (int i = 0; i < 8; ++i) {
            float kvv = ks[l][d0 + i];
            acc[i][0] += kvv * vv.x; acc[i][1] += kvv * vv.y;
            acc[i][2] += kvv * vv.z; acc[i][3] += kvv * vv.w;
        }
    }
    float* out = KV + (size_t)(n * NCH + c) * (DFEAT * HD);
    #pragma unroll
    for (int i = 0; i < 8; ++i) {
        float4 o = {acc[i][0], acc[i][1], acc[i][2], acc[i][3]};
        *(float4*)&out[(d0 + i) * HD + m0] = o;
    }
    if (t < 128) {
        float s = 0.f;
        #pragma unroll
        for (int l = 0; l < CCH; ++l) s += ks[l][t];
        K1[(size_t)(n * NCH + c) * DFEAT + t] = s;
    }
}

// ---------------- in-place exclusive prefix over chunks (KV and K1)
__global__ __launch_bounds__(256) void prefix_kernel(float* __restrict__ KV, float* __restrict__ K1)
{
    const int bx = blockIdx.x, t = threadIdx.x;
    if (bx < 512) {
        const int n = bx >> 5;
        const int idx = (bx & 31) * 256 + t;        // 0..8191
        float* base = KV + (size_t)n * NCH * (DFEAT * HD) + idx;
        float run = 0.f;
        for (int c = 0; c < NCH; ++c) {
            float vv = base[(size_t)c * (DFEAT * HD)];
            base[(size_t)c * (DFEAT * HD)] = run;
            run += vv;
        }
    } else {
        const int idx = (bx - 512) * 256 + t;       // 0..2047
        const int n = idx >> 7, d = idx & 127;
        float* base = K1 + (size_t)n * NCH * DFEAT + d;
        float run = 0.f;
        for (int c = 0; c < NCH; ++c) {
            float vv = base[c * DFEAT];
            base[c * DFEAT] = run;
            run += vv;
        }
    }
}

// ---------------- intra-chunk causal attention + external prefix + normalize
__global__ __launch_bounds__(256) void attn_chunk_kernel(
    const float* __restrict__ qf, const float* __restrict__ kf,
    const float* __restrict__ vf, const float* __restrict__ KVpre,
    const float* __restrict__ K1pre, u16* __restrict__ Amb)
{
    const int n = blockIdx.x >> 5;
    const int c = blockIdx.x & 31;
    __shared__ float Qs[32][132];
    __shared__ float Ks[32][132];
    __shared__ float Vs[32][68];
    __shared__ float Asm[32][36];
    __shared__ float K1s[128];
    __shared__ float rowsum[32];
    const int t = threadIdx.x;
    const float* qbase = qf + (size_t)(n * LSEQ + c * CCH) * DFEAT;
    const float* kbase = kf + (size_t)(n * LSEQ + c * CCH) * DFEAT;
    const float* vbase = vf + (size_t)(n * LSEQ + c * CCH) * HD;
    #pragma unroll
    for (int it = 0; it < 4; ++it) {
        int idx = it * 256 + t;
        int row = idx >> 5, c4 = (idx & 31) << 2;
        *(float4*)&Qs[row][c4] = *(const float4*)&qbase[row * DFEAT + c4];
        *(float4*)&Ks[row][c4] = *(const float4*)&kbase[row * DFEAT + c4];
    }
    #pragma unroll
    for (int it = 0; it < 2; ++it) {
        int idx = it * 256 + t;
        int row = idx >> 4, c4 = (idx & 15) << 2;
        *(float4*)&Vs[row][c4] = *(const float4*)&vbase[row * HD + c4];
    }
    if (t < 128) K1s[t] = K1pre[(size_t)(n * NCH + c) * DFEAT + t];
    __syncthreads();

    // phase A: A[l][lp] = q_l . k_lp (causal-masked), plus row sums
    {
        const int l = t >> 3;
        const int lp0 = (t & 7) << 2;
        float a4[4] = {0.f, 0.f, 0.f, 0.f};
        #pragma unroll 4
        for (int d = 0; d < DFEAT; ++d) {
            float qv = Qs[l][d];
            a4[0] += qv * Ks[lp0 + 0][d];
            a4[1] += qv * Ks[lp0 + 1][d];
            a4[2] += qv * Ks[lp0 + 2][d];
            a4[3] += qv * Ks[lp0 + 3][d];
        }
        float part = 0.f;
        #pragma unroll
        for (int j = 0; j < 4; ++j) {
            float m = (lp0 + j <= l) ? a4[j] : 0.f;
            Asm[l][lp0 + j] = m;
            part += m;
        }
        part += __shfl_xor(part, 1);
        part += __shfl_xor(part, 2);
        part += __shfl_xor(part, 4);
        if ((t & 7) == 0) rowsum[l] = part;
    }
    __syncthreads();

    // phase C: qkv = Q @ S_prev + A_masked @ V ; denom = q.K1_prev + rowsum
    const int m0 = (t & 15) << 2;
    const int lA = (t >> 4) << 1;
    const float* Sp = KVpre + (size_t)(n * NCH + c) * (DFEAT * HD);
    float acc0[4] = {}, acc1[4] = {};
    float dex0 = 0.f, dex1 = 0.f;
    #pragma unroll 4
    for (int d = 0; d < DFEAT; ++d) {
        float q0 = Qs[lA][d], q1 = Qs[lA + 1][d];
        float4 sv = *(const float4*)&Sp[d * HD + m0];
        acc0[0] += q0 * sv.x; acc0[1] += q0 * sv.y; acc0[2] += q0 * sv.z; acc0[3] += q0 * sv.w;
        acc1[0] += q1 * sv.x; acc1[1] += q1 * sv.y; acc1[2] += q1 * sv.z; acc1[3] += q1 * sv.w;
        float k1 = K1s[d];
        dex0 += q0 * k1; dex1 += q1 * k1;
    }
    #pragma unroll
    for (int lp = 0; lp < CCH; ++lp) {
        float a0 = Asm[lA][lp], a1 = Asm[lA + 1][lp];
        float4 vv = *(const float4*)&Vs[lp][m0];
        acc0[0] += a0 * vv.x; acc0[1] += a0 * vv.y; acc0[2] += a0 * vv.z; acc0[3] += a0 * vv.w;
        acc1[0] += a1 * vv.x; acc1[1] += a1 * vv.y; acc1[2] += a1 * vv.z; acc1[3] += a1 * vv.w;
    }
    const float den0 = fmaxf(rowsum[lA] + dex0, 1e-6f);
    const float den1 = fmaxf(rowsum[lA + 1] + dex1, 1e-6f);
    const int bb = n >> 3, h = n & 7;
    {
        const int lg = c * CCH + lA;
        int r = lg * 2 + bb;
        ushort4 o0; o0.x = f2bf(acc0[0] / den0); o0.y = f2bf(acc0[1] / den0);
        o0.z = f2bf(acc0[2] / den0); o0.w = f2bf(acc0[3] / den0);
        *(ushort4*)&Amb[(size_t)r * EDIM + h * 64 + m0] = o0;
        r = (lg + 1) * 2 + bb;
        ushort4 o1; o1.x = f2bf(acc1[0] / den1); o1.y = f2bf(acc1[1] / den1);
        o1.z = f2bf(acc1[2] / den1); o1.w = f2bf(acc1[3] / den1);
        *(ushort4*)&Amb[(size_t)r * EDIM + h * 64 + m0] = o1;
    }
}

// ---------------- output projection via bf16 MFMA: out = Am @ Wo^T + bo
__global__ __launch_bounds__(256) void out_mfma_kernel(
    const u16* __restrict__ Amb, const u16* __restrict__ Wob,
    const float* __restrict__ bo, float* __restrict__ out)
{
    const int r0 = blockIdx.x * 128;
    const int j0 = blockIdx.y * 128;
    __shared__ short As[128 * 32];
    __shared__ short Bs[128 * 32];
    const int t = threadIdx.x;
    const int wave = t >> 6, lane = t & 63;
    const int wm = (wave & 1) * 64, wn = (wave >> 1) * 64;
    const int cl = lane & 15, rg4 = lane >> 4;
    f32x4 acc[4][4];
    #pragma unroll
    for (int fi = 0; fi < 4; ++fi)
        #pragma unroll
        for (int fj = 0; fj < 4; ++fj) acc[fi][fj] = (f32x4){0.f, 0.f, 0.f, 0.f};

    for (int kb = 0; kb < 512; kb += 32) {
        #pragma unroll
        for (int i = 0; i < 2; ++i) {
            int chunk = i * 256 + t;
            int row = chunk >> 2, kg = chunk & 3;
            async16(&As[(size_t)(i * 256 + wave * 64) * 8], Amb + (size_t)(r0 + row) * 512 + kb + kg * 8);
            async16(&Bs[(size_t)(i * 256 + wave * 64) * 8], Wob + (size_t)(j0 + row) * 512 + kb + kg * 8);
        }
        __syncthreads();
        bf16x8 af[4], bg[4];
        #pragma unroll
        for (int f = 0; f < 4; ++f) {
            af[f] = *(const bf16x8*)&As[(wm + f * 16 + cl) * 32 + rg4 * 8];
            bg[f] = *(const bf16x8*)&Bs[(wn + f * 16 + cl) * 32 + rg4 * 8];
        }
        #pragma unroll
        for (int fi = 0; fi < 4; ++fi)
            #pragma unroll
            for (int fj = 0; fj < 4; ++fj)
                acc[fi][fj] = __builtin_amdgcn_mfma_f32_16x16x32_bf16(af[fi], bg[fj], acc[fi][fj], 0, 0, 0);
        __syncthreads();
    }

    float bov[4];
    #pragma unroll
    for (int fj = 0; fj < 4; ++fj) bov[fj] = bo[j0 + wn + fj * 16 + cl];
    #pragma unroll
    for (int fi = 0; fi < 4; ++fi)
        #pragma unroll
        for (int rr = 0; rr < 4; ++rr) {
            const int row_g = r0 + wm + fi * 16 + rg4 * 4 + rr;
            #pragma unroll
            for (int fj = 0; fj < 4; ++fj)
                out[(size_t)row_g * EDIM + j0 + wn + fj * 16 + cl] = acc[fi][fj][rr] + bov[fj];
        }
}

extern "C" void kernel_launch(void* const* d_in, const int* in_sizes, int n_in,
                              void* d_out, int out_size, void* d_ws, size_t ws_size,
                              hipStream_t stream) {
    const float* X  = (const float*)d_in[0];
    const float* Wq = (const float*)d_in[1]; const float* bq = (const float*)d_in[2];
    const float* Wk = (const float*)d_in[3]; const float* bk = (const float*)d_in[4];
    const float* Wv = (const float*)d_in[5]; const float* bv = (const float*)d_in[6];
    const float* Wo = (const float*)d_in[7]; const float* bo = (const float*)d_in[8];
    float* out = (float*)d_out;
    float* ws = (float*)d_ws;
    float* qf = ws;                         // 2,097,152 f
    float* kf = ws + 2097152;               // 2,097,152 f
    float* vf = ws + 4194304;               // 1,048,576 f
    float* KV = ws + 5242880;               // 4,194,304 f
    float* K1 = ws + 9437184;               //    65,536 f
    u16*   Amb = (u16*)(ws + 9502720);      // 1,048,576 bf16 (524,288 f)
    u16*   Xb  = (u16*)(ws + 10027008);     // 1,048,576 bf16
    u16*   Wb  = (u16*)(ws + 10551296);     // 4 x 262,144 bf16  (total ~44.3 MB)

    hipLaunchKernelGGL(cast_kernel, dim3(2048), dim3(256), 0, stream,
                       X, Wq, Wk, Wv, Wo, Xb, Wb);
    hipLaunchKernelGGL(qkv_mfma_kernel, dim3(16, 4, 3), dim3(256), 0, stream,
                       Xb, Wb, bq, bk, bv, qf, kf, vf);
    hipLaunchKernelGGL(chunk_sum_kernel, dim3(512), dim3(256), 0, stream, kf, vf, KV, K1);
    hipLaunchKernelGGL(prefix_kernel, dim3(520), dim3(256), 0, stream, KV, K1);
    hipLaunchKernelGGL(attn_chunk_kernel, dim3(512), dim3(256), 0, stream,
                       qf, kf, vf, KV, K1, Amb);
    hipLaunchKernelGGL(out_mfma_kernel, dim3(16, 4), dim3(256), 0, stream,
                       Amb, Wb + 786432, bo, out);
}

// Round 3
// 119.435 us; speedup vs baseline: 1.5383x; 1.1543x over previous
//
#include <hip/hip_runtime.h>
#include <math.h>

#define LSEQ 1024
#define EDIM 512
#define HD 64
#define CCH 32
#define NCH 32
#define DFEAT 128

typedef unsigned short u16;
typedef short bf16x8 __attribute__((ext_vector_type(8)));
typedef float f32x4 __attribute__((ext_vector_type(4)));

__device__ __forceinline__ u16 f2bf(float f) {
    unsigned u = __float_as_uint(f);
    unsigned r = (u + 0x7fffu + ((u >> 16) & 1u)) >> 16;
    return (u16)r;
}
__device__ __forceinline__ float bf2f(u16 x) {
    return __uint_as_float((unsigned)x << 16);
}
__device__ __forceinline__ void async16(void* lds, const void* g) {
    __builtin_amdgcn_global_load_lds(
        (const __attribute__((address_space(1))) unsigned int*)g,
        (__attribute__((address_space(3))) unsigned int*)lds, 16, 0, 0);
}

// ---------------- cast fp32 -> bf16 for X and the 4 weight matrices
__global__ __launch_bounds__(256) void cast_kernel(
    const float* __restrict__ X,  const float* __restrict__ Wq,
    const float* __restrict__ Wk, const float* __restrict__ Wv,
    const float* __restrict__ Wo, u16* __restrict__ Xb, u16* __restrict__ Wb)
{
    int i = blockIdx.x * 256 + threadIdx.x;   // one float4 group per thread
    const float* src; u16* dst; int off;
    if (i < 262144)      { src = X;  dst = Xb;          off = i; }
    else if (i < 327680) { src = Wq; dst = Wb;          off = i - 262144; }
    else if (i < 393216) { src = Wk; dst = Wb + 262144; off = i - 327680; }
    else if (i < 458752) { src = Wv; dst = Wb + 524288; off = i - 393216; }
    else                 { src = Wo; dst = Wb + 786432; off = i - 458752; }
    float4 v = *(const float4*)&src[(size_t)off * 4];
    ushort4 o; o.x = f2bf(v.x); o.y = f2bf(v.y); o.z = f2bf(v.z); o.w = f2bf(v.w);
    *(ushort4*)&dst[(size_t)off * 4] = o;
}

// ---------------- QKV projection via bf16 MFMA, bf16 outputs in head layout
__global__ __launch_bounds__(256) void qkv_mfma_kernel(
    const u16* __restrict__ Xb, const u16* __restrict__ Wb,
    const float* __restrict__ bq, const float* __restrict__ bk, const float* __restrict__ bv,
    u16* __restrict__ qf, u16* __restrict__ kf, u16* __restrict__ vf)
{
    const int z = blockIdx.z;
    const u16* __restrict__ W = Wb + (size_t)z * 262144;
    const float* __restrict__ bias = (z == 0) ? bq : (z == 1) ? bk : bv;
    const int r0 = blockIdx.x * 128;
    const int j0 = blockIdx.y * 128;
    __shared__ u16 As[128 * 32];
    __shared__ u16 Bs[128 * 32];
    const int t = threadIdx.x;
    const int wave = t >> 6, lane = t & 63;
    const int wm = (wave & 1) * 64, wn = (wave >> 1) * 64;
    const int cl = lane & 15, rg4 = lane >> 4;
    f32x4 acc[4][4];
    #pragma unroll
    for (int fi = 0; fi < 4; ++fi)
        #pragma unroll
        for (int fj = 0; fj < 4; ++fj) acc[fi][fj] = (f32x4){0.f, 0.f, 0.f, 0.f};

    for (int kb = 0; kb < 512; kb += 32) {
        #pragma unroll
        for (int i = 0; i < 2; ++i) {
            int chunk = i * 256 + t;
            int row = chunk >> 2, kg = chunk & 3;
            async16(&As[(size_t)(i * 256 + wave * 64) * 8], Xb + (size_t)(r0 + row) * 512 + kb + kg * 8);
            async16(&Bs[(size_t)(i * 256 + wave * 64) * 8], W  + (size_t)(j0 + row) * 512 + kb + kg * 8);
        }
        __syncthreads();
        bf16x8 af[4], bg[4];
        #pragma unroll
        for (int f = 0; f < 4; ++f) {
            af[f] = *(const bf16x8*)&As[(wm + f * 16 + cl) * 32 + rg4 * 8];
            bg[f] = *(const bf16x8*)&Bs[(wn + f * 16 + cl) * 32 + rg4 * 8];
        }
        #pragma unroll
        for (int fi = 0; fi < 4; ++fi)
            #pragma unroll
            for (int fj = 0; fj < 4; ++fj)
                acc[fi][fj] = __builtin_amdgcn_mfma_f32_16x16x32_bf16(af[fi], bg[fj], acc[fi][fj], 0, 0, 0);
        __syncthreads();
    }

    float biasv[4];
    #pragma unroll
    for (int fj = 0; fj < 4; ++fj) biasv[fj] = bias[j0 + wn + fj * 16 + cl];
    #pragma unroll
    for (int fi = 0; fi < 4; ++fi) {
        #pragma unroll
        for (int rr = 0; rr < 4; ++rr) {
            const int row_g = r0 + wm + fi * 16 + rg4 * 4 + rr;
            const int l = row_g >> 1, bb = row_g & 1;
            if (z < 2) {
                float ang = 1.5707963267948966f * (float)(l + 1) * (1.0f / 1024.0f);
                float sv, cv;
                sincosf(ang, &sv, &cv);
                u16* __restrict__ dst = (z == 0) ? qf : kf;
                #pragma unroll
                for (int fj = 0; fj < 4; ++fj) {
                    const int jg = j0 + wn + fj * 16 + cl;
                    float y = fmaxf(acc[fi][fj][rr] + biasv[fj], 0.f);
                    const int h = jg >> 6, d = jg & 63;
                    size_t base = (size_t)((bb * 8 + h) * LSEQ + l) * DFEAT;
                    dst[base + d]      = f2bf(y * sv);
                    dst[base + d + 64] = f2bf(y * cv);
                }
            } else {
                #pragma unroll
                for (int fj = 0; fj < 4; ++fj) {
                    const int jg = j0 + wn + fj * 16 + cl;
                    float y = acc[fi][fj][rr] + biasv[fj];
                    const int h = jg >> 6, d = jg & 63;
                    vf[(size_t)((bb * 8 + h) * LSEQ + l) * HD + d] = f2bf(y);
                }
            }
        }
    }
}

// ---------------- per-chunk KV sums via MFMA: KVc[n][c][m][d] = sum_l V[l][m]*K[l][d]
__global__ __launch_bounds__(256) void chunk_sum_kernel(
    const u16* __restrict__ kf, const u16* __restrict__ vf,
    float* __restrict__ KVc, float* __restrict__ K1c)
{
    const int n = blockIdx.x >> 5;
    const int c = blockIdx.x & 31;
    __shared__ u16 Ks[32 * 128];   // l-major (async contiguous)
    __shared__ u16 VT[64 * 32];    // transposed: [m][l]
    const int t = threadIdx.x;
    const int wave = t >> 6, lane = t & 63;
    const int cl = lane & 15, rg4 = lane >> 4;
    const u16* kbase = kf + (size_t)(n * LSEQ + c * CCH) * DFEAT;
    const u16* vbase = vf + (size_t)(n * LSEQ + c * CCH) * HD;
    #pragma unroll
    for (int i = 0; i < 2; ++i)
        async16(&Ks[(size_t)(i * 256 + wave * 64) * 8], kbase + (size_t)(i * 256 + t) * 8);
    {   // transpose V chunk into VT: wave w covers l = 8w..8w+7, lane = m
        u16 tmp[8];
        #pragma unroll
        for (int j = 0; j < 8; ++j) tmp[j] = vbase[(wave * 8 + j) * HD + lane];
        *(bf16x8*)&VT[lane * 32 + wave * 8] = *(bf16x8*)tmp;
    }
    __syncthreads();

    // A-frag: V^T tile (m = wave*16+cl, k=l contiguous)
    bf16x8 af = *(const bf16x8*)&VT[(wave * 16 + cl) * 32 + rg4 * 8];
    f32x4 acc[8];
    #pragma unroll
    for (int ni = 0; ni < 8; ++ni) {
        u16 bt[8];
        #pragma unroll
        for (int j = 0; j < 8; ++j)
            bt[j] = Ks[(rg4 * 8 + j) * 128 + ni * 16 + cl];
        acc[ni] = __builtin_amdgcn_mfma_f32_16x16x32_bf16(af, *(bf16x8*)bt,
                                                          (f32x4){0.f,0.f,0.f,0.f}, 0, 0, 0);
    }
    float* out = KVc + (size_t)(n * NCH + c) * (HD * DFEAT);
    #pragma unroll
    for (int ni = 0; ni < 8; ++ni)
        #pragma unroll
        for (int r = 0; r < 4; ++r) {
            int m = wave * 16 + rg4 * 4 + r;
            out[(size_t)m * 128 + ni * 16 + cl] = acc[ni][r];
        }
    if (t < 128) {
        float s = 0.f;
        #pragma unroll
        for (int l = 0; l < 32; ++l) s += bf2f(Ks[l * 128 + t]);
        K1c[(size_t)(n * NCH + c) * DFEAT + t] = s;
    }
}

// ---------------- exclusive prefix over chunks; KV -> bf16 Sp_t, K1 -> fp32
__global__ __launch_bounds__(256) void prefix_kernel(
    const float* __restrict__ KVc, const float* __restrict__ K1c,
    u16* __restrict__ Spt, float* __restrict__ K1p)
{
    const int bx = blockIdx.x, t = threadIdx.x;
    if (bx < 512) {
        const int n = bx >> 5;
        const int e = (bx & 31) * 256 + t;   // 0..8191 (m*128+d)
        const float* src = KVc + (size_t)n * NCH * 8192 + e;
        u16* dst = Spt + (size_t)n * NCH * 8192 + e;
        float v[32];
        #pragma unroll
        for (int c = 0; c < 32; ++c) v[c] = src[(size_t)c * 8192];
        float run = 0.f;
        #pragma unroll
        for (int c = 0; c < 32; ++c) { dst[(size_t)c * 8192] = f2bf(run); run += v[c]; }
    } else {
        const int idx = (bx - 512) * 256 + t;  // 0..2047
        const int n = idx >> 7, d = idx & 127;
        const float* src = K1c + (size_t)n * NCH * DFEAT + d;
        float* dst = K1p + (size_t)n * NCH * DFEAT + d;
        float v[32];
        #pragma unroll
        for (int c = 0; c < 32; ++c) v[c] = src[c * DFEAT];
        float run = 0.f;
        #pragma unroll
        for (int c = 0; c < 32; ++c) { dst[c * DFEAT] = run; run += v[c]; }
    }
}

// ---------------- intra-chunk attention via MFMA + prefix terms + normalize
__global__ __launch_bounds__(256) void attn_kernel(
    const u16* __restrict__ qf, const u16* __restrict__ kf, const u16* __restrict__ vf,
    const u16* __restrict__ Spt, const float* __restrict__ K1p,
    u16* __restrict__ Amb)
{
    const int n = blockIdx.x >> 5;
    const int c = blockIdx.x & 31;
    __shared__ u16 Qs[32 * 136];   // padded rows: conflict-optimal b128 reads
    __shared__ u16 Ks[32 * 136];
    __shared__ u16 VT[64 * 32];    // [m][l]
    __shared__ u16 Am[32 * 32];    // masked A, bf16, l-major
    __shared__ float K1s[128];
    __shared__ float dsum2[2][32]; // per-nj rowsums (fp32)
    __shared__ float qk1[32];
    const int t = threadIdx.x;
    const int wave = t >> 6, lane = t & 63;
    const int cl = lane & 15, rg4 = lane >> 4;
    const int mi = wave >> 1, nh = wave & 1;

    const u16* qbase = qf + (size_t)(n * LSEQ + c * CCH) * DFEAT;
    const u16* kbase = kf + (size_t)(n * LSEQ + c * CCH) * DFEAT;
    const u16* vbase = vf + (size_t)(n * LSEQ + c * CCH) * HD;
    const u16* spbase = Spt + (size_t)(n * NCH + c) * 8192;

    // prefetch S_prev B-frags straight from global (contiguous 16B per lane)
    bf16x8 spf[2][4];
    #pragma unroll
    for (int ni2 = 0; ni2 < 2; ++ni2)
        #pragma unroll
        for (int ks = 0; ks < 4; ++ks)
            spf[ni2][ks] = *(const bf16x8*)&spbase[((2 * nh + ni2) * 16 + cl) * 128 + ks * 32 + rg4 * 8];

    // stage Q,K into padded LDS
    #pragma unroll
    for (int i = 0; i < 2; ++i) {
        int chunk = i * 256 + t;            // 0..511
        int row = chunk >> 4, c8 = chunk & 15;
        *(bf16x8*)&Qs[row * 136 + c8 * 8] = *(const bf16x8*)&qbase[row * 128 + c8 * 8];
        *(bf16x8*)&Ks[row * 136 + c8 * 8] = *(const bf16x8*)&kbase[row * 128 + c8 * 8];
    }
    {   // V transpose
        u16 tmp[8];
        #pragma unroll
        for (int j = 0; j < 8; ++j) tmp[j] = vbase[(wave * 8 + j) * HD + lane];
        *(bf16x8*)&VT[lane * 32 + wave * 8] = *(bf16x8*)tmp;
    }
    if (t < 128) K1s[t] = K1p[(size_t)(n * NCH + c) * DFEAT + t];
    __syncthreads();

    // QK^T tile (mi, nh)
    f32x4 a_acc = (f32x4){0.f, 0.f, 0.f, 0.f};
    #pragma unroll
    for (int ks = 0; ks < 4; ++ks) {
        bf16x8 aq = *(const bf16x8*)&Qs[(mi * 16 + cl) * 136 + ks * 32 + rg4 * 8];
        bf16x8 bk = *(const bf16x8*)&Ks[(nh * 16 + cl) * 136 + ks * 32 + rg4 * 8];
        a_acc = __builtin_amdgcn_mfma_f32_16x16x32_bf16(aq, bk, a_acc, 0, 0, 0);
    }
    // mask, fp32 rowsum (shfl over the 16-lane column group), write bf16 A
    #pragma unroll
    for (int r = 0; r < 4; ++r) {
        int l_loc = mi * 16 + rg4 * 4 + r;
        int lp_loc = nh * 16 + cl;
        float v = (lp_loc <= l_loc) ? a_acc[r] : 0.f;
        Am[l_loc * 32 + lp_loc] = f2bf(v);
        float s = v;
        s += __shfl_xor(s, 1); s += __shfl_xor(s, 2);
        s += __shfl_xor(s, 4); s += __shfl_xor(s, 8);
        if (cl == 0) dsum2[nh][l_loc] = s;
    }
    {   // q . K1_prev per row: 8 lanes per row, 16 d each
        int row = wave * 8 + (lane >> 3), seg = lane & 7;
        float s = 0.f;
        #pragma unroll
        for (int j = 0; j < 16; ++j) {
            int d = seg * 16 + j;
            s += bf2f(Qs[row * 136 + d]) * K1s[d];
        }
        s += __shfl_xor(s, 1); s += __shfl_xor(s, 2); s += __shfl_xor(s, 4);
        if (seg == 0) qk1[row] = s;
    }
    __syncthreads();

    // C = Q @ S_prev + A_masked @ V   (tiles (mi, 2nh..2nh+1))
    f32x4 oacc[2] = {(f32x4){0.f,0.f,0.f,0.f}, (f32x4){0.f,0.f,0.f,0.f}};
    #pragma unroll
    for (int ks = 0; ks < 4; ++ks) {
        bf16x8 aq = *(const bf16x8*)&Qs[(mi * 16 + cl) * 136 + ks * 32 + rg4 * 8];
        #pragma unroll
        for (int ni2 = 0; ni2 < 2; ++ni2)
            oacc[ni2] = __builtin_amdgcn_mfma_f32_16x16x32_bf16(aq, spf[ni2][ks], oacc[ni2], 0, 0, 0);
    }
    {
        bf16x8 aa = *(const bf16x8*)&Am[(mi * 16 + cl) * 32 + rg4 * 8];
        #pragma unroll
        for (int ni2 = 0; ni2 < 2; ++ni2) {
            bf16x8 bv = *(const bf16x8*)&VT[((2 * nh + ni2) * 16 + cl) * 32 + rg4 * 8];
            oacc[ni2] = __builtin_amdgcn_mfma_f32_16x16x32_bf16(aa, bv, oacc[ni2], 0, 0, 0);
        }
    }
    // normalize + scatter to Amb (bf16, row r = l*2+b, col h*64+m)
    const int bb = n >> 3, h = n & 7;
    #pragma unroll
    for (int r = 0; r < 4; ++r) {
        int l_loc = mi * 16 + rg4 * 4 + r;
        float den = fmaxf(dsum2[0][l_loc] + dsum2[1][l_loc] + qk1[l_loc], 1e-6f);
        float inv = 1.0f / den;
        int rrow = (c * CCH + l_loc) * 2 + bb;
        #pragma unroll
        for (int ni2 = 0; ni2 < 2; ++ni2) {
            int m = (2 * nh + ni2) * 16 + cl;
            Amb[(size_t)rrow * EDIM + h * 64 + m] = f2bf(oacc[ni2][r] * inv);
        }
    }
}

// ---------------- output projection via bf16 MFMA: out = Am @ Wo^T + bo
__global__ __launch_bounds__(256) void out_mfma_kernel(
    const u16* __restrict__ Amb, const u16* __restrict__ Wob,
    const float* __restrict__ bo, float* __restrict__ out)
{
    const int r0 = blockIdx.x * 128;
    const int j0 = blockIdx.y * 128;
    __shared__ u16 As[128 * 32];
    __shared__ u16 Bs[128 * 32];
    const int t = threadIdx.x;
    const int wave = t >> 6, lane = t & 63;
    const int wm = (wave & 1) * 64, wn = (wave >> 1) * 64;
    const int cl = lane & 15, rg4 = lane >> 4;
    f32x4 acc[4][4];
    #pragma unroll
    for (int fi = 0; fi < 4; ++fi)
        #pragma unroll
        for (int fj = 0; fj < 4; ++fj) acc[fi][fj] = (f32x4){0.f, 0.f, 0.f, 0.f};

    for (int kb = 0; kb < 512; kb += 32) {
        #pragma unroll
        for (int i = 0; i < 2; ++i) {
            int chunk = i * 256 + t;
            int row = chunk >> 2, kg = chunk & 3;
            async16(&As[(size_t)(i * 256 + wave * 64) * 8], Amb + (size_t)(r0 + row) * 512 + kb + kg * 8);
            async16(&Bs[(size_t)(i * 256 + wave * 64) * 8], Wob + (size_t)(j0 + row) * 512 + kb + kg * 8);
        }
        __syncthreads();
        bf16x8 af[4], bg[4];
        #pragma unroll
        for (int f = 0; f < 4; ++f) {
            af[f] = *(const bf16x8*)&As[(wm + f * 16 + cl) * 32 + rg4 * 8];
            bg[f] = *(const bf16x8*)&Bs[(wn + f * 16 + cl) * 32 + rg4 * 8];
        }
        #pragma unroll
        for (int fi = 0; fi < 4; ++fi)
            #pragma unroll
            for (int fj = 0; fj < 4; ++fj)
                acc[fi][fj] = __builtin_amdgcn_mfma_f32_16x16x32_bf16(af[fi], bg[fj], acc[fi][fj], 0, 0, 0);
        __syncthreads();
    }

    float bov[4];
    #pragma unroll
    for (int fj = 0; fj < 4; ++fj) bov[fj] = bo[j0 + wn + fj * 16 + cl];
    #pragma unroll
    for (int fi = 0; fi < 4; ++fi)
        #pragma unroll
        for (int rr = 0; rr < 4; ++rr) {
            const int row_g = r0 + wm + fi * 16 + rg4 * 4 + rr;
            #pragma unroll
            for (int fj = 0; fj < 4; ++fj)
                out[(size_t)row_g * EDIM + j0 + wn + fj * 16 + cl] = acc[fi][fj][rr] + bov[fj];
        }
}

extern "C" void kernel_launch(void* const* d_in, const int* in_sizes, int n_in,
                              void* d_out, int out_size, void* d_ws, size_t ws_size,
                              hipStream_t stream) {
    const float* X  = (const float*)d_in[0];
    const float* Wq = (const float*)d_in[1]; const float* bq = (const float*)d_in[2];
    const float* Wk = (const float*)d_in[3]; const float* bk = (const float*)d_in[4];
    const float* Wv = (const float*)d_in[5]; const float* bv = (const float*)d_in[6];
    const float* Wo = (const float*)d_in[7]; const float* bo = (const float*)d_in[8];
    float* out = (float*)d_out;
    char* base = (char*)d_ws;
    u16*   qf  = (u16*)(base + 0);           // 16*1024*128 bf16 = 4 MB
    u16*   kf  = (u16*)(base + 4194304);     // 4 MB
    u16*   vf  = (u16*)(base + 8388608);     // 2 MB
    float* KVc = (float*)(base + 10485760);  // 16*32*64*128 f32 = 16 MB
    float* K1c = (float*)(base + 27262976);  // 256 KB
    u16*   Spt = (u16*)(base + 27525120);    // 8 MB
    float* K1p = (float*)(base + 35913728);  // 256 KB
    u16*   Amb = (u16*)(base + 36175872);    // 2 MB
    u16*   Xb  = (u16*)(base + 38273024);    // 2 MB
    u16*   Wb  = (u16*)(base + 40370176);    // 4 MB  (total ~44.6 MB)

    hipLaunchKernelGGL(cast_kernel, dim3(2048), dim3(256), 0, stream,
                       X, Wq, Wk, Wv, Wo, Xb, Wb);
    hipLaunchKernelGGL(qkv_mfma_kernel, dim3(16, 4, 3), dim3(256), 0, stream,
                       Xb, Wb, bq, bk, bv, qf, kf, vf);
    hipLaunchKernelGGL(chunk_sum_kernel, dim3(512), dim3(256), 0, stream, kf, vf, KVc, K1c);
    hipLaunchKernelGGL(prefix_kernel, dim3(520), dim3(256), 0, stream, KVc, K1c, Spt, K1p);
    hipLaunchKernelGGL(attn_kernel, dim3(512), dim3(256), 0, stream,
                       qf, kf, vf, Spt, K1p, Amb);
    hipLaunchKernelGGL(out_mfma_kernel, dim3(16, 4), dim3(256), 0, stream,
                       Amb, Wb + 786432, bo, out);
}